// Round 4
// baseline (1182.408 us; speedup 1.0000x reference)
//
#include <hip/hip_runtime.h>
#include <hip/hip_bf16.h>
#include <stdint.h>

#define BB 8
#define NN 2048
#define MM 2048
#define DD 2048
#define LN_EPS 1e-5f
#define SM_SCALE 0.022097086912079608f  // 2048^-0.5

typedef __bf16 bf16_t;
typedef __attribute__((ext_vector_type(8))) __bf16 bf16x8;
typedef __attribute__((ext_vector_type(4))) float f32x4;

#define AS1(p) ((const __attribute__((address_space(1))) void*)(p))
#define AS3(p) ((__attribute__((address_space(3))) void*)(p))

__device__ __forceinline__ void wave_reduce2(float& a, float& b) {
#pragma unroll
  for (int off = 32; off > 0; off >>= 1) {
    a += __shfl_down(a, off, 64);
    b += __shfl_down(b, off, 64);
  }
}

// ---- column mean over N:  xmean[b][d] += sum_n x[b][n][d] / N ----
__global__ __launch_bounds__(256) void colmean_kernel(const float* __restrict__ x,
                                                      float* __restrict__ xmean) {
  const int d = blockIdx.x * 256 + threadIdx.x;
  const int b = blockIdx.z;
  const int n0 = blockIdx.y * 128;
  const float* p = x + ((size_t)b * NN + n0) * DD + d;
  float s = 0.f;
#pragma unroll 8
  for (int i = 0; i < 128; ++i) s += p[(size_t)i * DD];
  atomicAdd(&xmean[b * DD + d], s * (1.0f / NN));
}

// ---- LN over last dim (no affine), f32 in -> bf16 out ----
__global__ __launch_bounds__(256) void ln_x_kernel(const float* __restrict__ x,
                                                   bf16_t* __restrict__ out) {
  __shared__ float sa[4], sb[4];
  const size_t row = blockIdx.x;
  const float* xr = x + row * DD;
  const int tid = threadIdx.x;
  f32x4 v0 = *(const f32x4*)(xr + tid * 8);
  f32x4 v1 = *(const f32x4*)(xr + tid * 8 + 4);
  float s = 0.f, s2 = 0.f;
#pragma unroll
  for (int k = 0; k < 4; ++k) {
    s += v0[k] + v1[k];
    s2 += v0[k] * v0[k] + v1[k] * v1[k];
  }
  wave_reduce2(s, s2);
  const int wid = tid >> 6, lid = tid & 63;
  if (lid == 0) { sa[wid] = s; sb[wid] = s2; }
  __syncthreads();
  s = sa[0] + sa[1] + sa[2] + sa[3];
  s2 = sb[0] + sb[1] + sb[2] + sb[3];
  const float mu = s * (1.f / DD);
  const float var = s2 * (1.f / DD) - mu * mu;
  const float rstd = rsqrtf(var + LN_EPS);
  bf16x8 o;
#pragma unroll
  for (int k = 0; k < 4; ++k) {
    o[k] = (__bf16)((v0[k] - mu) * rstd);
    o[k + 4] = (__bf16)((v1[k] - mu) * rstd);
  }
  *(bf16x8*)(out + row * DD + tid * 8) = o;
}

// ---- LN(g - xmean) -> bf16 ----
__global__ __launch_bounds__(256) void ln_g_kernel(const float* __restrict__ g,
                                                   const float* __restrict__ xmean,
                                                   bf16_t* __restrict__ out) {
  __shared__ float sa[4], sb[4];
  const size_t row = blockIdx.x;       // b*MM + m
  const int b = (int)(row >> 11);      // MM = 2048
  const float* gr = g + row * DD;
  const float* xm = xmean + (size_t)b * DD;
  const int tid = threadIdx.x;
  f32x4 v0 = *(const f32x4*)(gr + tid * 8);
  f32x4 v1 = *(const f32x4*)(gr + tid * 8 + 4);
  f32x4 m0 = *(const f32x4*)(xm + tid * 8);
  f32x4 m1 = *(const f32x4*)(xm + tid * 8 + 4);
  float s = 0.f, s2 = 0.f;
#pragma unroll
  for (int k = 0; k < 4; ++k) {
    v0[k] -= m0[k];
    v1[k] -= m1[k];
    s += v0[k] + v1[k];
    s2 += v0[k] * v0[k] + v1[k] * v1[k];
  }
  wave_reduce2(s, s2);
  const int wid = tid >> 6, lid = tid & 63;
  if (lid == 0) { sa[wid] = s; sb[wid] = s2; }
  __syncthreads();
  s = sa[0] + sa[1] + sa[2] + sa[3];
  s2 = sb[0] + sb[1] + sb[2] + sb[3];
  const float mu = s * (1.f / DD);
  const float var = s2 * (1.f / DD) - mu * mu;
  const float rstd = rsqrtf(var + LN_EPS);
  bf16x8 o;
#pragma unroll
  for (int k = 0; k < 4; ++k) {
    o[k] = (__bf16)((v0[k] - mu) * rstd);
    o[k + 4] = (__bf16)((v1[k] - mu) * rstd);
  }
  *(bf16x8*)(out + row * DD + tid * 8) = o;
}

// ---- f32 -> bf16 convert (weights) ----
__global__ __launch_bounds__(256) void cvt_kernel(const float* __restrict__ in,
                                                  bf16_t* __restrict__ out, int n8) {
  const int i = blockIdx.x * 256 + threadIdx.x;
  if (i >= n8) return;
  f32x4 a = *(const f32x4*)(in + (size_t)i * 8);
  f32x4 b = *(const f32x4*)(in + (size_t)i * 8 + 4);
  bf16x8 o;
#pragma unroll
  for (int k = 0; k < 4; ++k) {
    o[k] = (__bf16)a[k];
    o[k + 4] = (__bf16)b[k];
  }
  *(bf16x8*)(out + (size_t)i * 8) = o;
}

// ---- bf16 [M][D] -> [D][M] transpose per batch ----
__global__ __launch_bounds__(256) void transpose_kernel(const unsigned short* __restrict__ in,
                                                        unsigned short* __restrict__ out) {
  __shared__ unsigned short tile[32][33];
  const int b = blockIdx.z;
  const int m0 = blockIdx.y * 32, d0 = blockIdx.x * 32;
  const unsigned short* src = in + (size_t)b * MM * DD;
  unsigned short* dst = out + (size_t)b * DD * MM;
  const int tx = threadIdx.x, ty = threadIdx.y;
#pragma unroll
  for (int i = 0; i < 32; i += 8)
    tile[ty + i][tx] = src[(size_t)(m0 + ty + i) * DD + d0 + tx];
  __syncthreads();
#pragma unroll
  for (int i = 0; i < 32; i += 8)
    dst[(size_t)(d0 + ty + i) * MM + m0 + tx] = tile[tx][ty + i];
}

// ---- scaled softmax over rows of bf16 scores, in place ----
__global__ __launch_bounds__(256) void softmax_kernel(bf16_t* __restrict__ sc) {
  __shared__ float sh[4];
  const size_t row = blockIdx.x;
  bf16_t* pr = sc + row * MM;
  const int tid = threadIdx.x;
  const int wid = tid >> 6, lid = tid & 63;
  bf16x8 v = *(const bf16x8*)(pr + tid * 8);
  float f[8];
  float m = -1e30f;
#pragma unroll
  for (int k = 0; k < 8; ++k) {
    f[k] = (float)v[k];
    m = fmaxf(m, f[k]);
  }
#pragma unroll
  for (int off = 32; off > 0; off >>= 1) m = fmaxf(m, __shfl_down(m, off, 64));
  if (lid == 0) sh[wid] = m;
  __syncthreads();
  m = fmaxf(fmaxf(sh[0], sh[1]), fmaxf(sh[2], sh[3]));
  float s = 0.f;
#pragma unroll
  for (int k = 0; k < 8; ++k) {
    f[k] = __expf((f[k] - m) * SM_SCALE);
    s += f[k];
  }
  __syncthreads();
#pragma unroll
  for (int off = 32; off > 0; off >>= 1) s += __shfl_down(s, off, 64);
  if (lid == 0) sh[wid] = s;
  __syncthreads();
  s = sh[0] + sh[1] + sh[2] + sh[3];
  const float inv = 1.f / s;
  bf16x8 o;
#pragma unroll
  for (int k = 0; k < 8; ++k) o[k] = (__bf16)(f[k] * inv);
  *(bf16x8*)(pr + tid * 8) = o;
}

// ---- C = A * B^T, 128x128 tile, BK=32, bf16 MFMA ----
// MODE 0: bf16 store.  MODE 1: f32 store with residual add (resid + acc).
template <int MODE>
__global__ __launch_bounds__(256) void gemm_bt_kernel(
    const bf16_t* __restrict__ A, const bf16_t* __restrict__ Bm,
    void* __restrict__ C, const float* __restrict__ resid,
    size_t sA, size_t sB) {
  __shared__ bf16_t As[128 * 32];
  __shared__ bf16_t Bs[128 * 32];
  const int tid = threadIdx.x;
  const int lane = tid & 63;
  const int wid = tid >> 6;
  const int wr = wid >> 1, wc = wid & 1;
  const int bz = blockIdx.z;
  const int m0 = blockIdx.y * 128;
  const int n0 = blockIdx.x * 128;
  const bf16_t* Ab = A + (size_t)bz * sA;
  const bf16_t* Bb = Bm + (size_t)bz * sB;
  f32x4 acc[4][4] = {};

  const int e0 = tid * 8;
  const int r0 = e0 >> 5, c0 = e0 & 31;  // staging pass 0
  const int e1 = e0 + 2048;
  const int r1 = e1 >> 5, c1 = e1 & 31;  // staging pass 1
  const int fr = lane & 15;
  const int kg = (lane >> 4) * 8;

  for (int k0 = 0; k0 < 2048; k0 += 32) {
    __builtin_amdgcn_global_load_lds(AS1(Ab + (size_t)(m0 + r0) * 2048 + k0 + c0), AS3(As + e0), 16, 0, 0);
    __builtin_amdgcn_global_load_lds(AS1(Ab + (size_t)(m0 + r1) * 2048 + k0 + c1), AS3(As + e1), 16, 0, 0);
    __builtin_amdgcn_global_load_lds(AS1(Bb + (size_t)(n0 + r0) * 2048 + k0 + c0), AS3(Bs + e0), 16, 0, 0);
    __builtin_amdgcn_global_load_lds(AS1(Bb + (size_t)(n0 + r1) * 2048 + k0 + c1), AS3(Bs + e1), 16, 0, 0);
    __syncthreads();
    bf16x8 af[4], bv[4];
#pragma unroll
    for (int i = 0; i < 4; ++i)
      af[i] = *(const bf16x8*)(As + (wr * 64 + i * 16 + fr) * 32 + kg);
#pragma unroll
    for (int j = 0; j < 4; ++j)
      bv[j] = *(const bf16x8*)(Bs + (wc * 64 + j * 16 + fr) * 32 + kg);
#pragma unroll
    for (int i = 0; i < 4; ++i)
#pragma unroll
      for (int j = 0; j < 4; ++j)
        acc[i][j] = __builtin_amdgcn_mfma_f32_16x16x32_bf16(af[i], bv[j], acc[i][j], 0, 0, 0);
    __syncthreads();
  }

  const int cr = (lane >> 4) * 4;
  const int cc = lane & 15;
  const size_t cbase = (size_t)bz * 2048 * 2048;
#pragma unroll
  for (int i = 0; i < 4; ++i) {
#pragma unroll
    for (int j = 0; j < 4; ++j) {
#pragma unroll
      for (int t = 0; t < 4; ++t) {
        const int r = m0 + wr * 64 + i * 16 + cr + t;
        const int c = n0 + wc * 64 + j * 16 + cc;
        const size_t off = cbase + (size_t)r * 2048 + c;
        if (MODE == 0)
          ((bf16_t*)C)[off] = (__bf16)acc[i][j][t];
        else
          ((float*)C)[off] = resid[off] + acc[i][j][t];
      }
    }
  }
}

extern "C" void kernel_launch(void* const* d_in, const int* in_sizes, int n_in,
                              void* d_out, int out_size, void* d_ws, size_t ws_size,
                              hipStream_t stream) {
  const float* x = (const float*)d_in[0];
  const float* g = (const float*)d_in[1];
  const float* Wq = (const float*)d_in[2];
  const float* Wg = (const float*)d_in[3];
  float* out = (float*)d_out;

  uint8_t* ws = (uint8_t*)d_ws;
  const size_t SZ = (size_t)BB * NN * DD * 2;  // 64 MiB per bf16 tensor
  bf16_t* q_bf   = (bf16_t*)(ws + 0 * SZ);
  bf16_t* gc_bf  = (bf16_t*)(ws + 1 * SZ);
  bf16_t* gcT_bf = (bf16_t*)(ws + 2 * SZ);
  bf16_t* relq   = (bf16_t*)(ws + 3 * SZ);
  bf16_t* relg   = (bf16_t*)(ws + 4 * SZ);
  bf16_t* scores = (bf16_t*)(ws + 5 * SZ);  // softmax in place -> probs
  bf16_t* Wq_bf  = (bf16_t*)(ws + 6 * SZ);
  bf16_t* Wg_bf  = (bf16_t*)(ws + 6 * SZ + (size_t)DD * DD * 2);
  float*  xmean  = (float*)(ws + 6 * SZ + (size_t)DD * DD * 4);

  const size_t TEN = (size_t)NN * DD;  // per-batch elements (2048*2048)

  // 0) zero xmean accumulator
  hipMemsetAsync(xmean, 0, (size_t)BB * DD * sizeof(float), stream);

  // 1) weight conversion f32 -> bf16
  const int n8 = DD * DD / 8;
  cvt_kernel<<<dim3((n8 + 255) / 256), dim3(256), 0, stream>>>(Wq, Wq_bf, n8);
  cvt_kernel<<<dim3((n8 + 255) / 256), dim3(256), 0, stream>>>(Wg, Wg_bf, n8);

  // 2) xmean[b][d]
  colmean_kernel<<<dim3(DD / 256, NN / 128, BB), dim3(256), 0, stream>>>(x, xmean);

  // 3) q = LN(x); gc = LN(g - xmean)
  ln_x_kernel<<<dim3(BB * NN), dim3(256), 0, stream>>>(x, q_bf);
  ln_g_kernel<<<dim3(BB * MM), dim3(256), 0, stream>>>(g, xmean, gc_bf);

  // 4) gcT for the PV GEMM
  transpose_kernel<<<dim3(DD / 32, MM / 32, BB), dim3(32, 8), 0, stream>>>(
      (const unsigned short*)gc_bf, (unsigned short*)gcT_bf);

  // 5) rel_q = q @ Wq^T ; rel_g = gc @ Wg^T   (weight shared across batch: sB = 0)
  gemm_bt_kernel<0><<<dim3(DD / 128, NN / 128, BB), dim3(256), 0, stream>>>(
      q_bf, Wq_bf, (void*)relq, nullptr, TEN, 0);
  gemm_bt_kernel<0><<<dim3(DD / 128, MM / 128, BB), dim3(256), 0, stream>>>(
      gc_bf, Wg_bf, (void*)relg, nullptr, TEN, 0);

  // 6) scores = rel_q @ rel_g^T
  gemm_bt_kernel<0><<<dim3(MM / 128, NN / 128, BB), dim3(256), 0, stream>>>(
      relq, relg, (void*)scores, nullptr, TEN, TEN);

  // 7) softmax (scaled) in place
  softmax_kernel<<<dim3(BB * NN), dim3(256), 0, stream>>>(scores);

  // 8) out = x + probs @ gcT^T
  gemm_bt_kernel<1><<<dim3(DD / 128, NN / 128, BB), dim3(256), 0, stream>>>(
      scores, gcT_bf, (void*)out, x, TEN, TEN);
}

// Round 5
// 956.091 us; speedup vs baseline: 1.2367x; 1.2367x over previous
//
#include <hip/hip_runtime.h>
#include <hip/hip_bf16.h>
#include <stdint.h>

#define BB 8
#define NN 2048
#define MM 2048
#define DD 2048
#define LN_EPS 1e-5f
#define SM_SCALE 0.022097086912079608f  // 2048^-0.5

typedef __bf16 bf16_t;
typedef __attribute__((ext_vector_type(8))) __bf16 bf16x8;
typedef __attribute__((ext_vector_type(4))) float f32x4;

#define AS1(p) ((const __attribute__((address_space(1))) void*)(p))
#define AS3(p) ((__attribute__((address_space(3))) void*)(p))

__device__ __forceinline__ void wave_reduce2(float& a, float& b) {
#pragma unroll
  for (int off = 32; off > 0; off >>= 1) {
    a += __shfl_down(a, off, 64);
    b += __shfl_down(b, off, 64);
  }
}

// ---- column mean over N ----
__global__ __launch_bounds__(256) void colmean_kernel(const float* __restrict__ x,
                                                      float* __restrict__ xmean) {
  const int d = blockIdx.x * 256 + threadIdx.x;
  const int b = blockIdx.z;
  const int n0 = blockIdx.y * 128;
  const float* p = x + ((size_t)b * NN + n0) * DD + d;
  float s = 0.f;
#pragma unroll 8
  for (int i = 0; i < 128; ++i) s += p[(size_t)i * DD];
  atomicAdd(&xmean[b * DD + d], s * (1.0f / NN));
}

// ---- LN over last dim (no affine), f32 in -> bf16 out ----
__global__ __launch_bounds__(256) void ln_x_kernel(const float* __restrict__ x,
                                                   bf16_t* __restrict__ out) {
  __shared__ float sa[4], sb[4];
  const size_t row = blockIdx.x;
  const float* xr = x + row * DD;
  const int tid = threadIdx.x;
  f32x4 v0 = *(const f32x4*)(xr + tid * 8);
  f32x4 v1 = *(const f32x4*)(xr + tid * 8 + 4);
  float s = 0.f, s2 = 0.f;
#pragma unroll
  for (int k = 0; k < 4; ++k) {
    s += v0[k] + v1[k];
    s2 += v0[k] * v0[k] + v1[k] * v1[k];
  }
  wave_reduce2(s, s2);
  const int wid = tid >> 6, lid = tid & 63;
  if (lid == 0) { sa[wid] = s; sb[wid] = s2; }
  __syncthreads();
  s = sa[0] + sa[1] + sa[2] + sa[3];
  s2 = sb[0] + sb[1] + sb[2] + sb[3];
  const float mu = s * (1.f / DD);
  const float var = s2 * (1.f / DD) - mu * mu;
  const float rstd = rsqrtf(var + LN_EPS);
  bf16x8 o;
#pragma unroll
  for (int k = 0; k < 4; ++k) {
    o[k] = (__bf16)((v0[k] - mu) * rstd);
    o[k + 4] = (__bf16)((v1[k] - mu) * rstd);
  }
  *(bf16x8*)(out + row * DD + tid * 8) = o;
}

// ---- LN(g - xmean) -> bf16 ----
__global__ __launch_bounds__(256) void ln_g_kernel(const float* __restrict__ g,
                                                   const float* __restrict__ xmean,
                                                   bf16_t* __restrict__ out) {
  __shared__ float sa[4], sb[4];
  const size_t row = blockIdx.x;
  const int b = (int)(row >> 11);
  const float* gr = g + row * DD;
  const float* xm = xmean + (size_t)b * DD;
  const int tid = threadIdx.x;
  f32x4 v0 = *(const f32x4*)(gr + tid * 8);
  f32x4 v1 = *(const f32x4*)(gr + tid * 8 + 4);
  f32x4 m0 = *(const f32x4*)(xm + tid * 8);
  f32x4 m1 = *(const f32x4*)(xm + tid * 8 + 4);
  float s = 0.f, s2 = 0.f;
#pragma unroll
  for (int k = 0; k < 4; ++k) {
    v0[k] -= m0[k];
    v1[k] -= m1[k];
    s += v0[k] + v1[k];
    s2 += v0[k] * v0[k] + v1[k] * v1[k];
  }
  wave_reduce2(s, s2);
  const int wid = tid >> 6, lid = tid & 63;
  if (lid == 0) { sa[wid] = s; sb[wid] = s2; }
  __syncthreads();
  s = sa[0] + sa[1] + sa[2] + sa[3];
  s2 = sb[0] + sb[1] + sb[2] + sb[3];
  const float mu = s * (1.f / DD);
  const float var = s2 * (1.f / DD) - mu * mu;
  const float rstd = rsqrtf(var + LN_EPS);
  bf16x8 o;
#pragma unroll
  for (int k = 0; k < 4; ++k) {
    o[k] = (__bf16)((v0[k] - mu) * rstd);
    o[k + 4] = (__bf16)((v1[k] - mu) * rstd);
  }
  *(bf16x8*)(out + row * DD + tid * 8) = o;
}

// ---- f32 -> bf16 convert (weights) ----
__global__ __launch_bounds__(256) void cvt_kernel(const float* __restrict__ in,
                                                  bf16_t* __restrict__ out, int n8) {
  const int i = blockIdx.x * 256 + threadIdx.x;
  if (i >= n8) return;
  f32x4 a = *(const f32x4*)(in + (size_t)i * 8);
  f32x4 b = *(const f32x4*)(in + (size_t)i * 8 + 4);
  bf16x8 o;
#pragma unroll
  for (int k = 0; k < 4; ++k) {
    o[k] = (__bf16)a[k];
    o[k + 4] = (__bf16)b[k];
  }
  *(bf16x8*)(out + (size_t)i * 8) = o;
}

// ---- bf16 [M][D] -> [D][M] transpose per batch ----
__global__ __launch_bounds__(256) void transpose_kernel(const unsigned short* __restrict__ in,
                                                        unsigned short* __restrict__ out) {
  __shared__ unsigned short tile[32][33];
  const int b = blockIdx.z;
  const int m0 = blockIdx.y * 32, d0 = blockIdx.x * 32;
  const unsigned short* src = in + (size_t)b * MM * DD;
  unsigned short* dst = out + (size_t)b * DD * MM;
  const int tx = threadIdx.x, ty = threadIdx.y;
#pragma unroll
  for (int i = 0; i < 32; i += 8)
    tile[ty + i][tx] = src[(size_t)(m0 + ty + i) * DD + d0 + tx];
  __syncthreads();
#pragma unroll
  for (int i = 0; i < 32; i += 8)
    dst[(size_t)(d0 + ty + i) * MM + m0 + tx] = tile[tx][ty + i];
}

// ---- scaled softmax over rows, in place ----
__global__ __launch_bounds__(256) void softmax_kernel(bf16_t* __restrict__ sc) {
  __shared__ float sh[4];
  const size_t row = blockIdx.x;
  bf16_t* pr = sc + row * MM;
  const int tid = threadIdx.x;
  const int wid = tid >> 6, lid = tid & 63;
  bf16x8 v = *(const bf16x8*)(pr + tid * 8);
  float f[8];
  float m = -1e30f;
#pragma unroll
  for (int k = 0; k < 8; ++k) {
    f[k] = (float)v[k];
    m = fmaxf(m, f[k]);
  }
#pragma unroll
  for (int off = 32; off > 0; off >>= 1) m = fmaxf(m, __shfl_down(m, off, 64));
  if (lid == 0) sh[wid] = m;
  __syncthreads();
  m = fmaxf(fmaxf(sh[0], sh[1]), fmaxf(sh[2], sh[3]));
  float s = 0.f;
#pragma unroll
  for (int k = 0; k < 8; ++k) {
    f[k] = __expf((f[k] - m) * SM_SCALE);
    s += f[k];
  }
  __syncthreads();
#pragma unroll
  for (int off = 32; off > 0; off >>= 1) s += __shfl_down(s, off, 64);
  if (lid == 0) sh[wid] = s;
  __syncthreads();
  s = sh[0] + sh[1] + sh[2] + sh[3];
  const float inv = 1.f / s;
  bf16x8 o;
#pragma unroll
  for (int k = 0; k < 8; ++k) o[k] = (__bf16)(f[k] * inv);
  *(bf16x8*)(pr + tid * 8) = o;
}

// ==== C = A * B^T, 256x256 tile, BK=64, 8 waves (2Mx4N), phase-split ====
// T1 XCD swizzle + T2 LDS XOR swizzle + T3/T4 counted-vmcnt phases + T5 setprio.
// LDS: 2 bufs x (A 256x64 + B 256x64) bf16 = 128 KiB (dynamic).
// Octant = 64 rows x 64 cols = one global_load_lds pass (512 thr x 16B).
// Phase ph of K-tile t computes quadrant (mh=ph>>1, nh=ph&1).
// Staging schedule (race-free: region issued only after its last reader's
// phase has fully retired behind a barrier):
//   ph0: A-oct{1,3}@t+1 (other buf)   ph1: B{0,1}@t+1
//   ph2: B{2,3}@t+1                   ph3: A-oct{0,2}@t+2 (cur buf, mh0
//        last read in ph1)
// Boundary (end ph3): s_waitcnt vmcnt(2) -- only tile t+2's A-mh0 floats.
// MODE 0: bf16 store. MODE 1: f32 store with residual add.
template <int MODE>
__global__ __launch_bounds__(512, 2) void gemm256_kernel(
    const bf16_t* __restrict__ A, const bf16_t* __restrict__ Bm,
    void* __restrict__ C, const float* __restrict__ resid,
    size_t sA, size_t sB) {
  extern __shared__ bf16_t lds[];
  const int tid = threadIdx.x;
  const int lane = tid & 63;
  const int wid = tid >> 6;
  const int wm = wid >> 2;  // 0..1
  const int wn = wid & 3;   // 0..3

  // T1: XCD-aware swizzle (gridDim.x == 512, %8==0 -> bijective)
  int bid = blockIdx.x;
  const int cpx = gridDim.x >> 3;
  bid = (bid & 7) * cpx + (bid >> 3);
  const int bz = bid >> 6;
  const int rem = bid & 63;
  const int m0 = (rem >> 3) << 8;
  const int n0 = (rem & 7) << 8;

  const bf16_t* Ab = A + (size_t)bz * sA;
  const bf16_t* Bb = Bm + (size_t)bz * sB;

  // staging map: thread -> (row in octant, pre-swizzled source col)
  const int srow = tid >> 3;                           // 0..63
  const int scol = ((tid & 7) ^ (srow & 7)) << 3;      // elements (T2 inverse swz)

  const int fr = lane & 15;
  const int kg = lane >> 4;
  const int swz = fr & 7;

  f32x4 acc[8][4] = {};

#define ISSUE_A(c, kt, o)                                                                  \
  __builtin_amdgcn_global_load_lds(                                                        \
      AS1(Ab + (size_t)(m0 + (o)*64 + srow) * 2048 + (kt)*64 + scol),                      \
      AS3(lds + (c)*32768 + (o)*4096 + tid * 8), 16, 0, 0)
#define ISSUE_B(c, kt, o)                                                                  \
  __builtin_amdgcn_global_load_lds(                                                        \
      AS1(Bb + (size_t)(n0 + (o)*64 + srow) * 2048 + (kt)*64 + scol),                      \
      AS3(lds + (c)*32768 + 16384 + (o)*4096 + tid * 8), 16, 0, 0)

  // prologue: tile 0 complete + A-mh0 octants of tile 1 (float across barrier)
  ISSUE_A(0, 0, 0); ISSUE_A(0, 0, 1); ISSUE_A(0, 0, 2); ISSUE_A(0, 0, 3);
  ISSUE_B(0, 0, 0); ISSUE_B(0, 0, 1); ISSUE_B(0, 0, 2); ISSUE_B(0, 0, 3);
  ISSUE_A(1, 1, 0); ISSUE_A(1, 1, 2);
  asm volatile("s_waitcnt vmcnt(2)" ::: "memory");
  __builtin_amdgcn_s_barrier();

  for (int t = 0; t < 32; ++t) {
    const int cur = t & 1;
    const int nxt = cur ^ 1;
    const bf16_t* Ar = lds + cur * 32768 + wm * 8192;
    const bf16_t* Br = lds + cur * 32768 + 16384 + (wn >> 1) * 8192 + (wn & 1) * 4096;
#pragma unroll
    for (int ph = 0; ph < 4; ++ph) {
      const int mh = ph >> 1, nh = ph & 1;
      bf16x8 af[4][2], bf[2][2];
#pragma unroll
      for (int i = 0; i < 4; ++i) {
        const int ra = (mh * 64 + i * 16 + fr) * 64;
#pragma unroll
        for (int ks = 0; ks < 2; ++ks)
          af[i][ks] = *(const bf16x8*)(Ar + ra + ((((ks << 2) + kg) ^ swz) << 3));
      }
#pragma unroll
      for (int j = 0; j < 2; ++j) {
        const int rb = (nh * 32 + j * 16 + fr) * 64;
#pragma unroll
        for (int ks = 0; ks < 2; ++ks)
          bf[j][ks] = *(const bf16x8*)(Br + rb + ((((ks << 2) + kg) ^ swz) << 3));
      }
      if (ph == 0 && t + 1 < 32) { ISSUE_A(nxt, t + 1, 1); ISSUE_A(nxt, t + 1, 3); }
      if (ph == 1 && t + 1 < 32) { ISSUE_B(nxt, t + 1, 0); ISSUE_B(nxt, t + 1, 1); }
      if (ph == 2 && t + 1 < 32) { ISSUE_B(nxt, t + 1, 2); ISSUE_B(nxt, t + 1, 3); }
      if (ph == 3 && t + 2 < 32) { ISSUE_A(cur, t + 2, 0); ISSUE_A(cur, t + 2, 2); }
      __builtin_amdgcn_s_barrier();
      __builtin_amdgcn_s_setprio(1);
#pragma unroll
      for (int i = 0; i < 4; ++i)
#pragma unroll
        for (int j = 0; j < 2; ++j)
#pragma unroll
          for (int ks = 0; ks < 2; ++ks)
            acc[mh * 4 + i][nh * 2 + j] = __builtin_amdgcn_mfma_f32_16x16x32_bf16(
                af[i][ks], bf[j][ks], acc[mh * 4 + i][nh * 2 + j], 0, 0, 0);
      __builtin_amdgcn_s_setprio(0);
      if (ph == 3) {
        if (t < 30) asm volatile("s_waitcnt vmcnt(2)" ::: "memory");
        else        asm volatile("s_waitcnt vmcnt(0)" ::: "memory");
      }
      __builtin_amdgcn_s_barrier();
    }
  }
#undef ISSUE_A
#undef ISSUE_B

  const int cr = kg << 2;
  const size_t cbase = (size_t)bz * 2048 * 2048;
#pragma unroll
  for (int mi = 0; mi < 8; ++mi) {
#pragma unroll
    for (int j = 0; j < 4; ++j) {
#pragma unroll
      for (int t4 = 0; t4 < 4; ++t4) {
        const int r = m0 + wm * 128 + mi * 16 + cr + t4;
        const int c = n0 + wn * 64 + j * 16 + fr;
        const size_t off = cbase + (size_t)r * 2048 + c;
        if (MODE == 0)
          ((bf16_t*)C)[off] = (__bf16)acc[mi][j][t4];
        else
          ((float*)C)[off] = resid[off] + acc[mi][j][t4];
      }
    }
  }
}

extern "C" void kernel_launch(void* const* d_in, const int* in_sizes, int n_in,
                              void* d_out, int out_size, void* d_ws, size_t ws_size,
                              hipStream_t stream) {
  const float* x = (const float*)d_in[0];
  const float* g = (const float*)d_in[1];
  const float* Wq = (const float*)d_in[2];
  const float* Wg = (const float*)d_in[3];
  float* out = (float*)d_out;

  uint8_t* ws = (uint8_t*)d_ws;
  const size_t SZ = (size_t)BB * NN * DD * 2;
  bf16_t* q_bf   = (bf16_t*)(ws + 0 * SZ);
  bf16_t* gc_bf  = (bf16_t*)(ws + 1 * SZ);
  bf16_t* gcT_bf = (bf16_t*)(ws + 2 * SZ);
  bf16_t* relq   = (bf16_t*)(ws + 3 * SZ);
  bf16_t* relg   = (bf16_t*)(ws + 4 * SZ);
  bf16_t* scores = (bf16_t*)(ws + 5 * SZ);
  bf16_t* Wq_bf  = (bf16_t*)(ws + 6 * SZ);
  bf16_t* Wg_bf  = (bf16_t*)(ws + 6 * SZ + (size_t)DD * DD * 2);
  float*  xmean  = (float*)(ws + 6 * SZ + (size_t)DD * DD * 4);

  const size_t TEN = (size_t)NN * DD;
  const int SMEM = 131072;
  hipFuncSetAttribute(reinterpret_cast<const void*>(gemm256_kernel<0>),
                      hipFuncAttributeMaxDynamicSharedMemorySize, SMEM);
  hipFuncSetAttribute(reinterpret_cast<const void*>(gemm256_kernel<1>),
                      hipFuncAttributeMaxDynamicSharedMemorySize, SMEM);

  hipMemsetAsync(xmean, 0, (size_t)BB * DD * sizeof(float), stream);

  const int n8 = DD * DD / 8;
  cvt_kernel<<<dim3((n8 + 255) / 256), dim3(256), 0, stream>>>(Wq, Wq_bf, n8);
  cvt_kernel<<<dim3((n8 + 255) / 256), dim3(256), 0, stream>>>(Wg, Wg_bf, n8);

  colmean_kernel<<<dim3(DD / 256, NN / 128, BB), dim3(256), 0, stream>>>(x, xmean);

  ln_x_kernel<<<dim3(BB * NN), dim3(256), 0, stream>>>(x, q_bf);
  ln_g_kernel<<<dim3(BB * MM), dim3(256), 0, stream>>>(g, xmean, gc_bf);

  transpose_kernel<<<dim3(DD / 32, MM / 32, BB), dim3(32, 8), 0, stream>>>(
      (const unsigned short*)gc_bf, (unsigned short*)gcT_bf);

  gemm256_kernel<0><<<dim3(512), dim3(512), SMEM, stream>>>(
      q_bf, Wq_bf, (void*)relq, nullptr, TEN, 0);
  gemm256_kernel<0><<<dim3(512), dim3(512), SMEM, stream>>>(
      gc_bf, Wg_bf, (void*)relg, nullptr, TEN, 0);

  gemm256_kernel<0><<<dim3(512), dim3(512), SMEM, stream>>>(
      relq, relg, (void*)scores, nullptr, TEN, TEN);

  softmax_kernel<<<dim3(BB * NN), dim3(256), 0, stream>>>(scores);

  gemm256_kernel<1><<<dim3(512), dim3(512), SMEM, stream>>>(
      scores, gcT_bf, (void*)out, x, TEN, TEN);
}

// Round 7
// 929.127 us; speedup vs baseline: 1.2726x; 1.0290x over previous
//
#include <hip/hip_runtime.h>
#include <hip/hip_bf16.h>
#include <stdint.h>

#define BB 8
#define NN 2048
#define MM 2048
#define DD 2048
#define LN_EPS 1e-5f
#define SM_SCALE 0.022097086912079608f  // 2048^-0.5

typedef __bf16 bf16_t;
typedef __attribute__((ext_vector_type(8))) __bf16 bf16x8;
typedef __attribute__((ext_vector_type(4))) float f32x4;

#define AS1(p) ((const __attribute__((address_space(1))) void*)(p))
#define AS3(p) ((__attribute__((address_space(3))) void*)(p))

__device__ __forceinline__ void wave_reduce2(float& a, float& b) {
#pragma unroll
  for (int off = 32; off > 0; off >>= 1) {
    a += __shfl_down(a, off, 64);
    b += __shfl_down(b, off, 64);
  }
}

// ---- column mean over N ----
__global__ __launch_bounds__(256) void colmean_kernel(const float* __restrict__ x,
                                                      float* __restrict__ xmean) {
  const int d = blockIdx.x * 256 + threadIdx.x;
  const int b = blockIdx.z;
  const int n0 = blockIdx.y * 128;
  const float* p = x + ((size_t)b * NN + n0) * DD + d;
  float s = 0.f;
#pragma unroll 8
  for (int i = 0; i < 128; ++i) s += p[(size_t)i * DD];
  atomicAdd(&xmean[b * DD + d], s * (1.0f / NN));
}

// ---- LN over last dim (no affine), f32 in -> bf16 out ----
__global__ __launch_bounds__(256) void ln_x_kernel(const float* __restrict__ x,
                                                   bf16_t* __restrict__ out) {
  __shared__ float sa[4], sb[4];
  const size_t row = blockIdx.x;
  const float* xr = x + row * DD;
  const int tid = threadIdx.x;
  f32x4 v0 = *(const f32x4*)(xr + tid * 8);
  f32x4 v1 = *(const f32x4*)(xr + tid * 8 + 4);
  float s = 0.f, s2 = 0.f;
#pragma unroll
  for (int k = 0; k < 4; ++k) {
    s += v0[k] + v1[k];
    s2 += v0[k] * v0[k] + v1[k] * v1[k];
  }
  wave_reduce2(s, s2);
  const int wid = tid >> 6, lid = tid & 63;
  if (lid == 0) { sa[wid] = s; sb[wid] = s2; }
  __syncthreads();
  s = sa[0] + sa[1] + sa[2] + sa[3];
  s2 = sb[0] + sb[1] + sb[2] + sb[3];
  const float mu = s * (1.f / DD);
  const float var = s2 * (1.f / DD) - mu * mu;
  const float rstd = rsqrtf(var + LN_EPS);
  bf16x8 o;
#pragma unroll
  for (int k = 0; k < 4; ++k) {
    o[k] = (__bf16)((v0[k] - mu) * rstd);
    o[k + 4] = (__bf16)((v1[k] - mu) * rstd);
  }
  *(bf16x8*)(out + row * DD + tid * 8) = o;
}

// ---- LN(g - xmean) -> bf16 ----
__global__ __launch_bounds__(256) void ln_g_kernel(const float* __restrict__ g,
                                                   const float* __restrict__ xmean,
                                                   bf16_t* __restrict__ out) {
  __shared__ float sa[4], sb[4];
  const size_t row = blockIdx.x;
  const int b = (int)(row >> 11);
  const float* gr = g + row * DD;
  const float* xm = xmean + (size_t)b * DD;
  const int tid = threadIdx.x;
  f32x4 v0 = *(const f32x4*)(gr + tid * 8);
  f32x4 v1 = *(const f32x4*)(gr + tid * 8 + 4);
  f32x4 m0 = *(const f32x4*)(xm + tid * 8);
  f32x4 m1 = *(const f32x4*)(xm + tid * 8 + 4);
  float s = 0.f, s2 = 0.f;
#pragma unroll
  for (int k = 0; k < 4; ++k) {
    v0[k] -= m0[k];
    v1[k] -= m1[k];
    s += v0[k] + v1[k];
    s2 += v0[k] * v0[k] + v1[k] * v1[k];
  }
  wave_reduce2(s, s2);
  const int wid = tid >> 6, lid = tid & 63;
  if (lid == 0) { sa[wid] = s; sb[wid] = s2; }
  __syncthreads();
  s = sa[0] + sa[1] + sa[2] + sa[3];
  s2 = sb[0] + sb[1] + sb[2] + sb[3];
  const float mu = s * (1.f / DD);
  const float var = s2 * (1.f / DD) - mu * mu;
  const float rstd = rsqrtf(var + LN_EPS);
  bf16x8 o;
#pragma unroll
  for (int k = 0; k < 4; ++k) {
    o[k] = (__bf16)((v0[k] - mu) * rstd);
    o[k + 4] = (__bf16)((v1[k] - mu) * rstd);
  }
  *(bf16x8*)(out + row * DD + tid * 8) = o;
}

// ---- f32 -> bf16 convert (weights) ----
__global__ __launch_bounds__(256) void cvt_kernel(const float* __restrict__ in,
                                                  bf16_t* __restrict__ out, int n8) {
  const int i = blockIdx.x * 256 + threadIdx.x;
  if (i >= n8) return;
  f32x4 a = *(const f32x4*)(in + (size_t)i * 8);
  f32x4 b = *(const f32x4*)(in + (size_t)i * 8 + 4);
  bf16x8 o;
#pragma unroll
  for (int k = 0; k < 4; ++k) {
    o[k] = (__bf16)a[k];
    o[k + 4] = (__bf16)b[k];
  }
  *(bf16x8*)(out + (size_t)i * 8) = o;
}

// ---- bf16 [M][D] -> [D][M] transpose per batch ----
__global__ __launch_bounds__(256) void transpose_kernel(const unsigned short* __restrict__ in,
                                                        unsigned short* __restrict__ out) {
  __shared__ unsigned short tile[32][33];
  const int b = blockIdx.z;
  const int m0 = blockIdx.y * 32, d0 = blockIdx.x * 32;
  const unsigned short* src = in + (size_t)b * MM * DD;
  unsigned short* dst = out + (size_t)b * DD * MM;
  const int tx = threadIdx.x, ty = threadIdx.y;
#pragma unroll
  for (int i = 0; i < 32; i += 8)
    tile[ty + i][tx] = src[(size_t)(m0 + ty + i) * DD + d0 + tx];
  __syncthreads();
#pragma unroll
  for (int i = 0; i < 32; i += 8)
    dst[(size_t)(d0 + ty + i) * MM + m0 + tx] = tile[tx][ty + i];
}

// ---- scaled softmax over rows, in place ----
__global__ __launch_bounds__(256) void softmax_kernel(bf16_t* __restrict__ sc) {
  __shared__ float sh[4];
  const size_t row = blockIdx.x;
  bf16_t* pr = sc + row * MM;
  const int tid = threadIdx.x;
  const int wid = tid >> 6, lid = tid & 63;
  bf16x8 v = *(const bf16x8*)(pr + tid * 8);
  float f[8];
  float m = -1e30f;
#pragma unroll
  for (int k = 0; k < 8; ++k) {
    f[k] = (float)v[k];
    m = fmaxf(m, f[k]);
  }
#pragma unroll
  for (int off = 32; off > 0; off >>= 1) m = fmaxf(m, __shfl_down(m, off, 64));
  if (lid == 0) sh[wid] = m;
  __syncthreads();
  m = fmaxf(fmaxf(sh[0], sh[1]), fmaxf(sh[2], sh[3]));
  float s = 0.f;
#pragma unroll
  for (int k = 0; k < 8; ++k) {
    f[k] = __expf((f[k] - m) * SM_SCALE);
    s += f[k];
  }
  __syncthreads();
#pragma unroll
  for (int off = 32; off > 0; off >>= 1) s += __shfl_down(s, off, 64);
  if (lid == 0) sh[wid] = s;
  __syncthreads();
  s = sh[0] + sh[1] + sh[2] + sh[3];
  const float inv = 1.f / s;
  bf16x8 o;
#pragma unroll
  for (int k = 0; k < 8; ++k) o[k] = (__bf16)(f[k] * inv);
  *(bf16x8*)(pr + tid * 8) = o;
}

// ==== C = A * B^T, 256x256 tile, BK=64, 8 waves (2Mx4N), phase-split ====
// Round 7 (race-fixed R6): corrected first-read ledger.
//   A octants: {0,2}=mh0 (read ph0,ph1), {1,3}=mh1 (read ph2,ph3).
//   B octant wn: read by wave-column wn at EVERY phase (nh splits octant
//   ROWS: lower half ph0/ph2, upper ph1/ph3) -> ALL B octants are
//   first-read at ph0.
// Entering invariant for tile t: {A0,A2,B0..B3}@t landed; Q=[A1,A3]@t.
//   ph0: READ(0,0); issue A0,A2,B0..B3 @t+1 (6)            [no wait/bar]
//   ph1: READ(0,1); WAITV(6) -> retires A1,A3@t; barrier
//   ph2: READ(1,0); issue A1,A3 @t+1 (2)                   [no wait/bar]
//   ph3: READ(1,1); WAITV(2) -> retires 6 @t+1; barrier
// 2 barriers/tile; every load has >=3.5 phases (~500cy) of MFMA cover;
// vmcnt never drains to 0 in the main loop. WAR on buf nxt: each staged
// region's previous contents were last read >=1 barrier earlier (checked
// per region). MODE 0: bf16 store. MODE 1: f32 store with residual add.
template <int MODE>
__global__ __launch_bounds__(512, 2) void gemm256_kernel(
    const bf16_t* __restrict__ A, const bf16_t* __restrict__ Bm,
    void* __restrict__ C, const float* __restrict__ resid,
    size_t sA, size_t sB) {
  extern __shared__ bf16_t lds[];
  const int tid = threadIdx.x;
  const int lane = tid & 63;
  const int wid = tid >> 6;
  const int wm = wid >> 2;  // 0..1
  const int wn = wid & 3;   // 0..3

  // T1: XCD-aware swizzle (gridDim.x == 512, %8==0 -> bijective)
  int bid = blockIdx.x;
  const int cpx = gridDim.x >> 3;
  bid = (bid & 7) * cpx + (bid >> 3);
  const int bz = bid >> 6;
  const int rem = bid & 63;
  const int m0 = (rem >> 3) << 8;
  const int n0 = (rem & 7) << 8;

  const bf16_t* Ab = A + (size_t)bz * sA;
  const bf16_t* Bb = Bm + (size_t)bz * sB;

  // staging map: thread -> (row in octant, pre-swizzled source col) [T2 inverse]
  const int srow = tid >> 3;
  const int scol = ((tid & 7) ^ (srow & 7)) << 3;

  const int fr = lane & 15;
  const int kg = lane >> 4;
  const int swz = fr & 7;

  f32x4 acc[8][4] = {};

#define ISSUE_A(c, kt, o)                                                                  \
  __builtin_amdgcn_global_load_lds(                                                        \
      AS1(Ab + (size_t)(m0 + (o)*64 + srow) * 2048 + (kt)*64 + scol),                      \
      AS3(lds + (c)*32768 + (o)*4096 + tid * 8), 16, 0, 0)
#define ISSUE_B(c, kt, o)                                                                  \
  __builtin_amdgcn_global_load_lds(                                                        \
      AS1(Bb + (size_t)(n0 + (o)*64 + srow) * 2048 + (kt)*64 + scol),                      \
      AS3(lds + (c)*32768 + 16384 + (o)*4096 + tid * 8), 16, 0, 0)

// read fragments for quadrant (mh,nh) of buf cur
#define READ_FRAGS(mh, nh)                                                                 \
  {                                                                                        \
    const bf16_t* Ar = lds + cur * 32768 + wm * 8192;                                      \
    const bf16_t* Br = lds + cur * 32768 + 16384 + wn * 4096;                              \
    _Pragma("unroll") for (int i = 0; i < 4; ++i) {                                        \
      const int ra = ((mh)*64 + i * 16 + fr) * 64;                                         \
      _Pragma("unroll") for (int ks = 0; ks < 2; ++ks)                                     \
          af[i][ks] = *(const bf16x8*)(Ar + ra + ((((ks << 2) + kg) ^ swz) << 3));         \
    }                                                                                      \
    _Pragma("unroll") for (int j = 0; j < 2; ++j) {                                        \
      const int rb = ((nh)*32 + j * 16 + fr) * 64;                                         \
      _Pragma("unroll") for (int ks = 0; ks < 2; ++ks)                                     \
          bf[j][ks] = *(const bf16x8*)(Br + rb + ((((ks << 2) + kg) ^ swz) << 3));         \
    }                                                                                      \
  }

#define MFMA_BLOCK(mh, nh)                                                                 \
  __builtin_amdgcn_s_setprio(1);                                                           \
  _Pragma("unroll") for (int i = 0; i < 4; ++i)                                            \
      _Pragma("unroll") for (int j = 0; j < 2; ++j)                                        \
          _Pragma("unroll") for (int ks = 0; ks < 2; ++ks)                                 \
              acc[(mh)*4 + i][(nh)*2 + j] = __builtin_amdgcn_mfma_f32_16x16x32_bf16(       \
                  af[i][ks], bf[j][ks], acc[(mh)*4 + i][(nh)*2 + j], 0, 0, 0);             \
  __builtin_amdgcn_s_setprio(0);

#define WAITV(n) asm volatile("s_waitcnt vmcnt(" #n ")" ::: "memory")

  // prologue: 6 early panels of tile 0, then A1,A3; retire the 6.
  ISSUE_A(0, 0, 0); ISSUE_A(0, 0, 2);
  ISSUE_B(0, 0, 0); ISSUE_B(0, 0, 1); ISSUE_B(0, 0, 2); ISSUE_B(0, 0, 3);
  ISSUE_A(0, 0, 1); ISSUE_A(0, 0, 3);
  WAITV(2);
  __builtin_amdgcn_s_barrier();

  bf16x8 af[4][2], bf[2][2];

  for (int t = 0; t < 31; ++t) {
    const int cur = t & 1;
    const int nxt = cur ^ 1;
    // ph0: quadrant (0,0) — issue all 6 early panels of t+1
    READ_FRAGS(0, 0);
    ISSUE_A(nxt, t + 1, 0); ISSUE_A(nxt, t + 1, 2);
    ISSUE_B(nxt, t + 1, 0); ISSUE_B(nxt, t + 1, 1);
    ISSUE_B(nxt, t + 1, 2); ISSUE_B(nxt, t + 1, 3);
    MFMA_BLOCK(0, 0);
    // ph1: (0,1) — retire A1,A3@t (2 oldest of 8)
    READ_FRAGS(0, 1);
    MFMA_BLOCK(0, 1);
    WAITV(6);
    __builtin_amdgcn_s_barrier();
    // ph2: (1,0) — issue late panels A1,A3@t+1
    READ_FRAGS(1, 0);
    ISSUE_A(nxt, t + 1, 1); ISSUE_A(nxt, t + 1, 3);
    MFMA_BLOCK(1, 0);
    // ph3: (1,1) — retire the 6 early panels of t+1
    READ_FRAGS(1, 1);
    MFMA_BLOCK(1, 1);
    WAITV(2);
    __builtin_amdgcn_s_barrier();
  }
  // tail tile t=31 (cur=1): no issues; drain A1,A3@31 before ph2
  {
    const int cur = 1;
    READ_FRAGS(0, 0);
    MFMA_BLOCK(0, 0);
    READ_FRAGS(0, 1);
    MFMA_BLOCK(0, 1);
    WAITV(0);
    __builtin_amdgcn_s_barrier();
    READ_FRAGS(1, 0);
    MFMA_BLOCK(1, 0);
    READ_FRAGS(1, 1);
    MFMA_BLOCK(1, 1);
  }
#undef ISSUE_A
#undef ISSUE_B
#undef READ_FRAGS
#undef MFMA_BLOCK
#undef WAITV

  const int cr = kg << 2;
  const size_t cbase = (size_t)bz * 2048 * 2048;
#pragma unroll
  for (int mi = 0; mi < 8; ++mi) {
#pragma unroll
    for (int j = 0; j < 4; ++j) {
#pragma unroll
      for (int t4 = 0; t4 < 4; ++t4) {
        const int r = m0 + wm * 128 + mi * 16 + cr + t4;
        const int c = n0 + wn * 64 + j * 16 + fr;
        const size_t off = cbase + (size_t)r * 2048 + c;
        if (MODE == 0)
          ((bf16_t*)C)[off] = (__bf16)acc[mi][j][t4];
        else
          ((float*)C)[off] = resid[off] + acc[mi][j][t4];
      }
    }
  }
}

extern "C" void kernel_launch(void* const* d_in, const int* in_sizes, int n_in,
                              void* d_out, int out_size, void* d_ws, size_t ws_size,
                              hipStream_t stream) {
  const float* x = (const float*)d_in[0];
  const float* g = (const float*)d_in[1];
  const float* Wq = (const float*)d_in[2];
  const float* Wg = (const float*)d_in[3];
  float* out = (float*)d_out;

  uint8_t* ws = (uint8_t*)d_ws;
  const size_t SZ = (size_t)BB * NN * DD * 2;
  bf16_t* q_bf   = (bf16_t*)(ws + 0 * SZ);
  bf16_t* gc_bf  = (bf16_t*)(ws + 1 * SZ);
  bf16_t* gcT_bf = (bf16_t*)(ws + 2 * SZ);
  bf16_t* relq   = (bf16_t*)(ws + 3 * SZ);
  bf16_t* relg   = (bf16_t*)(ws + 4 * SZ);
  bf16_t* scores = (bf16_t*)(ws + 5 * SZ);
  bf16_t* Wq_bf  = (bf16_t*)(ws + 6 * SZ);
  bf16_t* Wg_bf  = (bf16_t*)(ws + 6 * SZ + (size_t)DD * DD * 2);
  float*  xmean  = (float*)(ws + 6 * SZ + (size_t)DD * DD * 4);

  const size_t TEN = (size_t)NN * DD;
  const int SMEM = 131072;
  hipFuncSetAttribute(reinterpret_cast<const void*>(gemm256_kernel<0>),
                      hipFuncAttributeMaxDynamicSharedMemorySize, SMEM);
  hipFuncSetAttribute(reinterpret_cast<const void*>(gemm256_kernel<1>),
                      hipFuncAttributeMaxDynamicSharedMemorySize, SMEM);

  hipMemsetAsync(xmean, 0, (size_t)BB * DD * sizeof(float), stream);

  const int n8 = DD * DD / 8;
  cvt_kernel<<<dim3((n8 + 255) / 256), dim3(256), 0, stream>>>(Wq, Wq_bf, n8);
  cvt_kernel<<<dim3((n8 + 255) / 256), dim3(256), 0, stream>>>(Wg, Wg_bf, n8);

  colmean_kernel<<<dim3(DD / 256, NN / 128, BB), dim3(256), 0, stream>>>(x, xmean);

  ln_x_kernel<<<dim3(BB * NN), dim3(256), 0, stream>>>(x, q_bf);
  ln_g_kernel<<<dim3(BB * MM), dim3(256), 0, stream>>>(g, xmean, gc_bf);

  transpose_kernel<<<dim3(DD / 32, MM / 32, BB), dim3(32, 8), 0, stream>>>(
      (const unsigned short*)gc_bf, (unsigned short*)gcT_bf);

  gemm256_kernel<0><<<dim3(512), dim3(512), SMEM, stream>>>(
      q_bf, Wq_bf, (void*)relq, nullptr, TEN, 0);
  gemm256_kernel<0><<<dim3(512), dim3(512), SMEM, stream>>>(
      gc_bf, Wg_bf, (void*)relg, nullptr, TEN, 0);

  gemm256_kernel<0><<<dim3(512), dim3(512), SMEM, stream>>>(
      relq, relg, (void*)scores, nullptr, TEN, TEN);

  softmax_kernel<<<dim3(BB * NN), dim3(256), 0, stream>>>(scores);

  gemm256_kernel<1><<<dim3(512), dim3(512), SMEM, stream>>>(
      scores, gcT_bf, (void*)out, x, TEN, TEN);
}

// Round 8
// 882.884 us; speedup vs baseline: 1.3393x; 1.0524x over previous
//
#include <hip/hip_runtime.h>
#include <hip/hip_bf16.h>
#include <stdint.h>

#define BB 8
#define NN 2048
#define MM 2048
#define DD 2048
#define LN_EPS 1e-5f
#define SM_SCALE 0.022097086912079608f  // 2048^-0.5

typedef __bf16 bf16_t;
typedef __attribute__((ext_vector_type(8))) __bf16 bf16x8;
typedef __attribute__((ext_vector_type(4))) float f32x4;

#define AS1(p) ((const __attribute__((address_space(1))) void*)(p))
#define AS3(p) ((__attribute__((address_space(3))) void*)(p))

__device__ __forceinline__ void wave_reduce2(float& a, float& b) {
#pragma unroll
  for (int off = 32; off > 0; off >>= 1) {
    a += __shfl_down(a, off, 64);
    b += __shfl_down(b, off, 64);
  }
}

// ---- column mean over N ----
__global__ __launch_bounds__(256) void colmean_kernel(const float* __restrict__ x,
                                                      float* __restrict__ xmean) {
  const int d = blockIdx.x * 256 + threadIdx.x;
  const int b = blockIdx.z;
  const int n0 = blockIdx.y * 128;
  const float* p = x + ((size_t)b * NN + n0) * DD + d;
  float s = 0.f;
#pragma unroll 8
  for (int i = 0; i < 128; ++i) s += p[(size_t)i * DD];
  atomicAdd(&xmean[b * DD + d], s * (1.0f / NN));
}

// ---- LN over last dim (no affine), f32 in -> bf16 out ----
__global__ __launch_bounds__(256) void ln_x_kernel(const float* __restrict__ x,
                                                   bf16_t* __restrict__ out) {
  __shared__ float sa[4], sb[4];
  const size_t row = blockIdx.x;
  const float* xr = x + row * DD;
  const int tid = threadIdx.x;
  f32x4 v0 = *(const f32x4*)(xr + tid * 8);
  f32x4 v1 = *(const f32x4*)(xr + tid * 8 + 4);
  float s = 0.f, s2 = 0.f;
#pragma unroll
  for (int k = 0; k < 4; ++k) {
    s += v0[k] + v1[k];
    s2 += v0[k] * v0[k] + v1[k] * v1[k];
  }
  wave_reduce2(s, s2);
  const int wid = tid >> 6, lid = tid & 63;
  if (lid == 0) { sa[wid] = s; sb[wid] = s2; }
  __syncthreads();
  s = sa[0] + sa[1] + sa[2] + sa[3];
  s2 = sb[0] + sb[1] + sb[2] + sb[3];
  const float mu = s * (1.f / DD);
  const float var = s2 * (1.f / DD) - mu * mu;
  const float rstd = rsqrtf(var + LN_EPS);
  bf16x8 o;
#pragma unroll
  for (int k = 0; k < 4; ++k) {
    o[k] = (__bf16)((v0[k] - mu) * rstd);
    o[k + 4] = (__bf16)((v1[k] - mu) * rstd);
  }
  *(bf16x8*)(out + row * DD + tid * 8) = o;
}

// ---- LN(g - xmean) -> bf16 ----
__global__ __launch_bounds__(256) void ln_g_kernel(const float* __restrict__ g,
                                                   const float* __restrict__ xmean,
                                                   bf16_t* __restrict__ out) {
  __shared__ float sa[4], sb[4];
  const size_t row = blockIdx.x;
  const int b = (int)(row >> 11);
  const float* gr = g + row * DD;
  const float* xm = xmean + (size_t)b * DD;
  const int tid = threadIdx.x;
  f32x4 v0 = *(const f32x4*)(gr + tid * 8);
  f32x4 v1 = *(const f32x4*)(gr + tid * 8 + 4);
  f32x4 m0 = *(const f32x4*)(xm + tid * 8);
  f32x4 m1 = *(const f32x4*)(xm + tid * 8 + 4);
  float s = 0.f, s2 = 0.f;
#pragma unroll
  for (int k = 0; k < 4; ++k) {
    v0[k] -= m0[k];
    v1[k] -= m1[k];
    s += v0[k] + v1[k];
    s2 += v0[k] * v0[k] + v1[k] * v1[k];
  }
  wave_reduce2(s, s2);
  const int wid = tid >> 6, lid = tid & 63;
  if (lid == 0) { sa[wid] = s; sb[wid] = s2; }
  __syncthreads();
  s = sa[0] + sa[1] + sa[2] + sa[3];
  s2 = sb[0] + sb[1] + sb[2] + sb[3];
  const float mu = s * (1.f / DD);
  const float var = s2 * (1.f / DD) - mu * mu;
  const float rstd = rsqrtf(var + LN_EPS);
  bf16x8 o;
#pragma unroll
  for (int k = 0; k < 4; ++k) {
    o[k] = (__bf16)((v0[k] - mu) * rstd);
    o[k + 4] = (__bf16)((v1[k] - mu) * rstd);
  }
  *(bf16x8*)(out + row * DD + tid * 8) = o;
}

// ---- f32 -> bf16 convert (weights) ----
__global__ __launch_bounds__(256) void cvt_kernel(const float* __restrict__ in,
                                                  bf16_t* __restrict__ out, int n8) {
  const int i = blockIdx.x * 256 + threadIdx.x;
  if (i >= n8) return;
  f32x4 a = *(const f32x4*)(in + (size_t)i * 8);
  f32x4 b = *(const f32x4*)(in + (size_t)i * 8 + 4);
  bf16x8 o;
#pragma unroll
  for (int k = 0; k < 4; ++k) {
    o[k] = (__bf16)a[k];
    o[k + 4] = (__bf16)b[k];
  }
  *(bf16x8*)(out + (size_t)i * 8) = o;
}

// ---- bf16 [M][D] -> [D][M] transpose per batch ----
__global__ __launch_bounds__(256) void transpose_kernel(const unsigned short* __restrict__ in,
                                                        unsigned short* __restrict__ out) {
  __shared__ unsigned short tile[32][33];
  const int b = blockIdx.z;
  const int m0 = blockIdx.y * 32, d0 = blockIdx.x * 32;
  const unsigned short* src = in + (size_t)b * MM * DD;
  unsigned short* dst = out + (size_t)b * DD * MM;
  const int tx = threadIdx.x, ty = threadIdx.y;
#pragma unroll
  for (int i = 0; i < 32; i += 8)
    tile[ty + i][tx] = src[(size_t)(m0 + ty + i) * DD + d0 + tx];
  __syncthreads();
#pragma unroll
  for (int i = 0; i < 32; i += 8)
    dst[(size_t)(d0 + ty + i) * MM + m0 + tx] = tile[tx][ty + i];
}

// ---- scaled softmax over rows, in place ----
__global__ __launch_bounds__(256) void softmax_kernel(bf16_t* __restrict__ sc) {
  __shared__ float sh[4];
  const size_t row = blockIdx.x;
  bf16_t* pr = sc + row * MM;
  const int tid = threadIdx.x;
  const int wid = tid >> 6, lid = tid & 63;
  bf16x8 v = *(const bf16x8*)(pr + tid * 8);
  float f[8];
  float m = -1e30f;
#pragma unroll
  for (int k = 0; k < 8; ++k) {
    f[k] = (float)v[k];
    m = fmaxf(m, f[k]);
  }
#pragma unroll
  for (int off = 32; off > 0; off >>= 1) m = fmaxf(m, __shfl_down(m, off, 64));
  if (lid == 0) sh[wid] = m;
  __syncthreads();
  m = fmaxf(fmaxf(sh[0], sh[1]), fmaxf(sh[2], sh[3]));
  float s = 0.f;
#pragma unroll
  for (int k = 0; k < 8; ++k) {
    f[k] = __expf((f[k] - m) * SM_SCALE);
    s += f[k];
  }
  __syncthreads();
#pragma unroll
  for (int off = 32; off > 0; off >>= 1) s += __shfl_down(s, off, 64);
  if (lid == 0) sh[wid] = s;
  __syncthreads();
  s = sh[0] + sh[1] + sh[2] + sh[3];
  const float inv = 1.f / s;
  bf16x8 o;
#pragma unroll
  for (int k = 0; k < 8; ++k) o[k] = (__bf16)(f[k] * inv);
  *(bf16x8*)(pr + tid * 8) = o;
}

// ==== C = A * B^T, 256x256 tile, BK=64, 8 waves (2Mx4N), phase-split ====
// Round 8: identical sync/staging skeleton to (verified, race-free) R7;
// fragment reads hoisted so each LDS fragment is read ONCE per K-tile:
//   ph0: read af<-mh0 (8 b128) + bf0<-nh0 (4); MFMA (0,0)
//   ph1: read bf1<-nh1 (4);                    MFMA (0,1); WAITV(6)+bar
//   ph2: read af<-mh1 (8, same regs);          MFMA (1,0)
//   ph3: (no reads, frags held)                MFMA (1,1); WAITV(2)+bar
// 24 b128/wave/K-tile (was 48) -> LDS-read time ~halved, ~balances MFMA.
// Staging ledger unchanged: entering tile t, {A0,A2,B0..3}@t landed,
// Q=[A1,A3]@t; ph0 issues 6 early@t+1; WAITV(6) retires A1,A3@t before
// ph2 reads them; ph2 issues A1,A3@t+1; WAITV(2) retires 6 early@t+1.
// MODE 0: bf16 store. MODE 1: f32 store with residual add.
template <int MODE>
__global__ __launch_bounds__(512, 2) void gemm256_kernel(
    const bf16_t* __restrict__ A, const bf16_t* __restrict__ Bm,
    void* __restrict__ C, const float* __restrict__ resid,
    size_t sA, size_t sB) {
  extern __shared__ bf16_t lds[];
  const int tid = threadIdx.x;
  const int lane = tid & 63;
  const int wid = tid >> 6;
  const int wm = wid >> 2;  // 0..1
  const int wn = wid & 3;   // 0..3

  // T1: XCD-aware swizzle (gridDim.x == 512, %8==0 -> bijective)
  int bid = blockIdx.x;
  const int cpx = gridDim.x >> 3;
  bid = (bid & 7) * cpx + (bid >> 3);
  const int bz = bid >> 6;
  const int rem = bid & 63;
  const int m0 = (rem >> 3) << 8;
  const int n0 = (rem & 7) << 8;

  const bf16_t* Ab = A + (size_t)bz * sA;
  const bf16_t* Bb = Bm + (size_t)bz * sB;

  // staging map: thread -> (row in octant, pre-swizzled source col) [T2 inverse]
  const int srow = tid >> 3;
  const int scol = ((tid & 7) ^ (srow & 7)) << 3;

  const int fr = lane & 15;
  const int kg = lane >> 4;
  const int swz = fr & 7;

  f32x4 acc[8][4] = {};

#define ISSUE_A(c, kt, o)                                                                  \
  __builtin_amdgcn_global_load_lds(                                                        \
      AS1(Ab + (size_t)(m0 + (o)*64 + srow) * 2048 + (kt)*64 + scol),                      \
      AS3(lds + (c)*32768 + (o)*4096 + tid * 8), 16, 0, 0)
#define ISSUE_B(c, kt, o)                                                                  \
  __builtin_amdgcn_global_load_lds(                                                        \
      AS1(Bb + (size_t)(n0 + (o)*64 + srow) * 2048 + (kt)*64 + scol),                      \
      AS3(lds + (c)*32768 + 16384 + (o)*4096 + tid * 8), 16, 0, 0)

// read A fragments for row-half mh of buf cur into af
#define READ_A(mh)                                                                         \
  {                                                                                        \
    const bf16_t* Ar = lds + cur * 32768 + wm * 8192;                                      \
    _Pragma("unroll") for (int i = 0; i < 4; ++i) {                                        \
      const int ra = ((mh)*64 + i * 16 + fr) * 64;                                         \
      _Pragma("unroll") for (int ks = 0; ks < 2; ++ks)                                     \
          af[i][ks] = *(const bf16x8*)(Ar + ra + ((((ks << 2) + kg) ^ swz) << 3));         \
    }                                                                                      \
  }
// read B fragments for col-half nh of buf cur into dst
#define READ_B(dst, nh)                                                                    \
  {                                                                                        \
    const bf16_t* Br = lds + cur * 32768 + 16384 + wn * 4096;                              \
    _Pragma("unroll") for (int j = 0; j < 2; ++j) {                                        \
      const int rb = ((nh)*32 + j * 16 + fr) * 64;                                         \
      _Pragma("unroll") for (int ks = 0; ks < 2; ++ks)                                     \
          dst[j][ks] = *(const bf16x8*)(Br + rb + ((((ks << 2) + kg) ^ swz) << 3));        \
    }                                                                                      \
  }

#define MFMA_BLOCK(mh, nh, bfm)                                                            \
  __builtin_amdgcn_s_setprio(1);                                                           \
  _Pragma("unroll") for (int i = 0; i < 4; ++i)                                            \
      _Pragma("unroll") for (int j = 0; j < 2; ++j)                                        \
          _Pragma("unroll") for (int ks = 0; ks < 2; ++ks)                                 \
              acc[(mh)*4 + i][(nh)*2 + j] = __builtin_amdgcn_mfma_f32_16x16x32_bf16(       \
                  af[i][ks], bfm[j][ks], acc[(mh)*4 + i][(nh)*2 + j], 0, 0, 0);            \
  __builtin_amdgcn_s_setprio(0);

#define WAITV(n) asm volatile("s_waitcnt vmcnt(" #n ")" ::: "memory")

  // prologue: 6 early panels of tile 0, then A1,A3; retire the 6.
  ISSUE_A(0, 0, 0); ISSUE_A(0, 0, 2);
  ISSUE_B(0, 0, 0); ISSUE_B(0, 0, 1); ISSUE_B(0, 0, 2); ISSUE_B(0, 0, 3);
  ISSUE_A(0, 0, 1); ISSUE_A(0, 0, 3);
  WAITV(2);
  __builtin_amdgcn_s_barrier();

  bf16x8 af[4][2], bf0[2][2], bf1[2][2];

  for (int t = 0; t < 31; ++t) {
    const int cur = t & 1;
    const int nxt = cur ^ 1;
    // ph0: (0,0) — read af(mh0)+bf0(nh0); issue all 6 early panels of t+1
    READ_A(0); READ_B(bf0, 0);
    ISSUE_A(nxt, t + 1, 0); ISSUE_A(nxt, t + 1, 2);
    ISSUE_B(nxt, t + 1, 0); ISSUE_B(nxt, t + 1, 1);
    ISSUE_B(nxt, t + 1, 2); ISSUE_B(nxt, t + 1, 3);
    MFMA_BLOCK(0, 0, bf0);
    // ph1: (0,1) — read bf1(nh1); retire A1,A3@t (2 oldest of 8)
    READ_B(bf1, 1);
    MFMA_BLOCK(0, 1, bf1);
    WAITV(6);
    __builtin_amdgcn_s_barrier();
    // ph2: (1,0) — re-load af(mh1); issue late panels A1,A3@t+1
    READ_A(1);
    ISSUE_A(nxt, t + 1, 1); ISSUE_A(nxt, t + 1, 3);
    MFMA_BLOCK(1, 0, bf0);
    // ph3: (1,1) — all frags held; retire the 6 early panels of t+1
    MFMA_BLOCK(1, 1, bf1);
    WAITV(2);
    __builtin_amdgcn_s_barrier();
  }
  // tail tile t=31 (cur=1): no issues; drain A1,A3@31 before mh1 reads
  {
    const int cur = 1;
    READ_A(0); READ_B(bf0, 0);
    MFMA_BLOCK(0, 0, bf0);
    READ_B(bf1, 1);
    MFMA_BLOCK(0, 1, bf1);
    WAITV(0);
    __builtin_amdgcn_s_barrier();
    READ_A(1);
    MFMA_BLOCK(1, 0, bf0);
    MFMA_BLOCK(1, 1, bf1);
  }
#undef ISSUE_A
#undef ISSUE_B
#undef READ_A
#undef READ_B
#undef MFMA_BLOCK
#undef WAITV

  const int cr = kg << 2;
  const size_t cbase = (size_t)bz * 2048 * 2048;
#pragma unroll
  for (int mi = 0; mi < 8; ++mi) {
#pragma unroll
    for (int j = 0; j < 4; ++j) {
#pragma unroll
      for (int t4 = 0; t4 < 4; ++t4) {
        const int r = m0 + wm * 128 + mi * 16 + cr + t4;
        const int c = n0 + wn * 64 + j * 16 + fr;
        const size_t off = cbase + (size_t)r * 2048 + c;
        if (MODE == 0)
          ((bf16_t*)C)[off] = (__bf16)acc[mi][j][t4];
        else
          ((float*)C)[off] = resid[off] + acc[mi][j][t4];
      }
    }
  }
}

extern "C" void kernel_launch(void* const* d_in, const int* in_sizes, int n_in,
                              void* d_out, int out_size, void* d_ws, size_t ws_size,
                              hipStream_t stream) {
  const float* x = (const float*)d_in[0];
  const float* g = (const float*)d_in[1];
  const float* Wq = (const float*)d_in[2];
  const float* Wg = (const float*)d_in[3];
  float* out = (float*)d_out;

  uint8_t* ws = (uint8_t*)d_ws;
  const size_t SZ = (size_t)BB * NN * DD * 2;
  bf16_t* q_bf   = (bf16_t*)(ws + 0 * SZ);
  bf16_t* gc_bf  = (bf16_t*)(ws + 1 * SZ);
  bf16_t* gcT_bf = (bf16_t*)(ws + 2 * SZ);
  bf16_t* relq   = (bf16_t*)(ws + 3 * SZ);
  bf16_t* relg   = (bf16_t*)(ws + 4 * SZ);
  bf16_t* scores = (bf16_t*)(ws + 5 * SZ);
  bf16_t* Wq_bf  = (bf16_t*)(ws + 6 * SZ);
  bf16_t* Wg_bf  = (bf16_t*)(ws + 6 * SZ + (size_t)DD * DD * 2);
  float*  xmean  = (float*)(ws + 6 * SZ + (size_t)DD * DD * 4);

  const size_t TEN = (size_t)NN * DD;
  const int SMEM = 131072;
  hipFuncSetAttribute(reinterpret_cast<const void*>(gemm256_kernel<0>),
                      hipFuncAttributeMaxDynamicSharedMemorySize, SMEM);
  hipFuncSetAttribute(reinterpret_cast<const void*>(gemm256_kernel<1>),
                      hipFuncAttributeMaxDynamicSharedMemorySize, SMEM);

  hipMemsetAsync(xmean, 0, (size_t)BB * DD * sizeof(float), stream);

  const int n8 = DD * DD / 8;
  cvt_kernel<<<dim3((n8 + 255) / 256), dim3(256), 0, stream>>>(Wq, Wq_bf, n8);
  cvt_kernel<<<dim3((n8 + 255) / 256), dim3(256), 0, stream>>>(Wg, Wg_bf, n8);

  colmean_kernel<<<dim3(DD / 256, NN / 128, BB), dim3(256), 0, stream>>>(x, xmean);

  ln_x_kernel<<<dim3(BB * NN), dim3(256), 0, stream>>>(x, q_bf);
  ln_g_kernel<<<dim3(BB * MM), dim3(256), 0, stream>>>(g, xmean, gc_bf);

  transpose_kernel<<<dim3(DD / 32, MM / 32, BB), dim3(32, 8), 0, stream>>>(
      (const unsigned short*)gc_bf, (unsigned short*)gcT_bf);

  gemm256_kernel<0><<<dim3(512), dim3(512), SMEM, stream>>>(
      q_bf, Wq_bf, (void*)relq, nullptr, TEN, 0);
  gemm256_kernel<0><<<dim3(512), dim3(512), SMEM, stream>>>(
      gc_bf, Wg_bf, (void*)relg, nullptr, TEN, 0);

  gemm256_kernel<0><<<dim3(512), dim3(512), SMEM, stream>>>(
      relq, relg, (void*)scores, nullptr, TEN, TEN);

  softmax_kernel<<<dim3(BB * NN), dim3(256), 0, stream>>>(scores);

  gemm256_kernel<1><<<dim3(512), dim3(512), SMEM, stream>>>(
      scores, gcT_bf, (void*)out, x, TEN, TEN);
}